// Round 7
// baseline (200.029 us; speedup 1.0000x reference)
//
#include <hip/hip_runtime.h>

// YOLO loss, round 7: r6 byte-gating + forced load-burst scheduling.
// Evidence r1-r6: time ∝ demanded bytes at ~2.5 TB/s; but r2 (compiler
// accidentally re-issued loads -> deepest request stream) sustained 3.26 TB/s
// demand / 2.34 TB/s HBM-only. So no hard 2.5 cap: rounds with VGPR=32 were
// scheduling-depth-bound (~4-6 loads in flight/wave). Fix: launch_bounds
// (256,4) = 128-VGPR budget, and load ALL of a cell's data into locals
// before computing, so ~21 independent loads (~170 lines/wave) are in
// flight; x16 waves/CU ≈ 2700 lines outstanding per CU (~10x r6).

#define SS 28
#define BLOCK 256

__global__ __launch_bounds__(BLOCK, 4) void yolo_main(
    const float* __restrict__ pred,     // [cells*30]
    const float4* __restrict__ tbox4,   // [cells]
    const float4* __restrict__ tcls4,   // [cells*5]
    const int*   __restrict__ mask,     // [cells]
    float4* __restrict__ block_part,    // [gridDim.x]
    int cells)
{
    int cell = blockIdx.x * BLOCK + threadIdx.x;

    float acc_cls = 0.f, acc_noobj = 0.f, acc_reg = 0.f, acc_cont = 0.f;

    if (cell < cells) {
        bool m = mask[cell] != 0;               // coalesced 4B
        const float* pc = pred + (size_t)cell * 30;

        if (!m) {
            // only the confidence terms are live
            float c1 = pc[4];
            float c2 = pc[9];
            acc_noobj = c1 * c1 + c2 * c2;      // *0.5 in finalize
        } else {
            // ---- BURST: issue all 21 loads into locals, no consumption ----
            const float2* p2 = (const float2*)pc;       // 8B-aligned (cell*120B)
            float2 q0  = p2[0],  q1  = p2[1],  q2  = p2[2],  q3  = p2[3];
            float2 q4  = p2[4],  q5  = p2[5],  q6  = p2[6],  q7  = p2[7];
            float2 q8  = p2[8],  q9  = p2[9],  q10 = p2[10], q11 = p2[11];
            float2 q12 = p2[12], q13 = p2[13], q14 = p2[14];

            const float4* t4 = tcls4 + (size_t)cell * 5;
            float4 tv0 = t4[0], tv1 = t4[1], tv2 = t4[2], tv3 = t4[3], tv4 = t4[4];

            float4 tb = tbox4[cell];

            // ---- consume ----
            float pr[30];
            pr[0]=q0.x;  pr[1]=q0.y;  pr[2]=q1.x;  pr[3]=q1.y;
            pr[4]=q2.x;  pr[5]=q2.y;  pr[6]=q3.x;  pr[7]=q3.y;
            pr[8]=q4.x;  pr[9]=q4.y;  pr[10]=q5.x; pr[11]=q5.y;
            pr[12]=q6.x; pr[13]=q6.y; pr[14]=q7.x; pr[15]=q7.y;
            pr[16]=q8.x; pr[17]=q8.y; pr[18]=q9.x; pr[19]=q9.y;
            pr[20]=q10.x;pr[21]=q10.y;pr[22]=q11.x;pr[23]=q11.y;
            pr[24]=q12.x;pr[25]=q12.y;pr[26]=q13.x;pr[27]=q13.y;
            pr[28]=q14.x;pr[29]=q14.y;

            float cls = 0.f;
            {
                float d;
                d = pr[10]-tv0.x; cls += d*d;  d = pr[11]-tv0.y; cls += d*d;
                d = pr[12]-tv0.z; cls += d*d;  d = pr[13]-tv0.w; cls += d*d;
                d = pr[14]-tv1.x; cls += d*d;  d = pr[15]-tv1.y; cls += d*d;
                d = pr[16]-tv1.z; cls += d*d;  d = pr[17]-tv1.w; cls += d*d;
                d = pr[18]-tv2.x; cls += d*d;  d = pr[19]-tv2.y; cls += d*d;
                d = pr[20]-tv2.z; cls += d*d;  d = pr[21]-tv2.w; cls += d*d;
                d = pr[22]-tv3.x; cls += d*d;  d = pr[23]-tv3.y; cls += d*d;
                d = pr[24]-tv3.z; cls += d*d;  d = pr[25]-tv3.w; cls += d*d;
                d = pr[26]-tv4.x; cls += d*d;  d = pr[27]-tv4.y; cls += d*d;
                d = pr[28]-tv4.z; cls += d*d;  d = pr[29]-tv4.w; cls += d*d;
            }
            acc_cls = cls;

            // IOU, exact reference arithmetic
            const float invS = 1.f / 28.f;
            float txc = tb.x * invS, tyc = tb.y * invS;
            float t0 = txc - 0.5f * tb.z, t1 = tyc - 0.5f * tb.w;
            float t2 = txc + 0.5f * tb.z, t3 = tyc + 0.5f * tb.w;
            float ta = (t2 - t0) * (t3 - t1);

            float b1xc = pr[0] * invS, b1yc = pr[1] * invS;
            float a0 = b1xc - 0.5f * pr[2], a1 = b1yc - 0.5f * pr[3];
            float a2 = b1xc + 0.5f * pr[2], a3 = b1yc + 0.5f * pr[3];
            float wx = fmaxf(fminf(a2, t2) - fmaxf(a0, t0), 0.f);
            float wy = fmaxf(fminf(a3, t3) - fmaxf(a1, t1), 0.f);
            float inter = wx * wy;
            float area1 = (a2 - a0) * (a3 - a1);
            float den = area1 + ta - inter;
            float iou1 = inter / (den > 0.f ? den : 1.f);

            float b2xc = pr[5] * invS, b2yc = pr[6] * invS;
            float c0 = b2xc - 0.5f * pr[7], c1 = b2yc - 0.5f * pr[8];
            float c2 = b2xc + 0.5f * pr[7], c3 = b2yc + 0.5f * pr[8];
            wx = fmaxf(fminf(c2, t2) - fmaxf(c0, t0), 0.f);
            wy = fmaxf(fminf(c3, t3) - fmaxf(c1, t1), 0.f);
            inter = wx * wy;
            float area2 = (c2 - c0) * (c3 - c1);
            den = area2 + ta - inter;
            float iou2 = inter / (den > 0.f ? den : 1.f);

            bool take1 = iou1 > iou2;
            float best_iou = take1 ? iou1 : iou2;
            float bbx = take1 ? pr[0] : pr[5];
            float bby = take1 ? pr[1] : pr[6];
            float bbw = take1 ? pr[2] : pr[7];
            float bbh = take1 ? pr[3] : pr[8];
            float bbc = take1 ? pr[4] : pr[9];

            float dx = bbx - tb.x, dy = bby - tb.y;
            float xy = dx * dx + dy * dy;

            // m==1 here: where(mask, v, 1.0) == v
            float dw = sqrtf(bbw) - sqrtf(tb.z);
            float dh = sqrtf(bbh) - sqrtf(tb.w);
            float wh = dw * dw + dh * dh;

            acc_reg = xy + wh;

            float dc = bbc - best_iou;
            acc_cont = dc * dc;
        }
    }

    // wave reduction (64 lanes)
    float4 v = make_float4(acc_cls, acc_noobj, acc_reg, acc_cont);
    #pragma unroll
    for (int off = 32; off >= 1; off >>= 1) {
        v.x += __shfl_down(v.x, off, 64);
        v.y += __shfl_down(v.y, off, 64);
        v.z += __shfl_down(v.z, off, 64);
        v.w += __shfl_down(v.w, off, 64);
    }
    __shared__ float4 sred[BLOCK / 64];
    int lane = threadIdx.x & 63;
    int wave = threadIdx.x >> 6;
    if (lane == 0) sred[wave] = v;
    __syncthreads();
    if (threadIdx.x == 0) {
        float4 r = sred[0];
        #pragma unroll
        for (int w = 1; w < BLOCK / 64; ++w) {
            r.x += sred[w].x; r.y += sred[w].y; r.z += sred[w].z; r.w += sred[w].w;
        }
        block_part[blockIdx.x] = r;
    }
}

__global__ __launch_bounds__(BLOCK) void yolo_final(
    const float4* __restrict__ part, int nparts, float* __restrict__ out, float invN)
{
    float4 v = make_float4(0.f, 0.f, 0.f, 0.f);
    for (int i = threadIdx.x; i < nparts; i += BLOCK) {
        float4 p = part[i];
        v.x += p.x; v.y += p.y; v.z += p.z; v.w += p.w;
    }
    #pragma unroll
    for (int off = 32; off >= 1; off >>= 1) {
        v.x += __shfl_down(v.x, off, 64);
        v.y += __shfl_down(v.y, off, 64);
        v.z += __shfl_down(v.z, off, 64);
        v.w += __shfl_down(v.w, off, 64);
    }
    __shared__ float4 sred[BLOCK / 64];
    int lane = threadIdx.x & 63;
    int wave = threadIdx.x >> 6;
    if (lane == 0) sred[wave] = v;
    __syncthreads();
    if (threadIdx.x == 0) {
        float4 r = sred[0];
        #pragma unroll
        for (int w = 1; w < BLOCK / 64; ++w) {
            r.x += sred[w].x; r.y += sred[w].y; r.z += sred[w].z; r.w += sred[w].w;
        }
        float cls    = r.x;
        float no_obj = 0.5f * r.y;   // L_NOOBJ
        float reg    = 5.0f * r.z;   // L_COORD
        float cont   = r.w;
        float total  = cls + no_obj + cont + reg;
        out[0] = total  * invN;
        out[1] = reg    * invN;
        out[2] = cont   * invN;
        out[3] = no_obj * invN;
        out[4] = cls    * invN;
    }
}

extern "C" void kernel_launch(void* const* d_in, const int* in_sizes, int n_in,
                              void* d_out, int out_size, void* d_ws, size_t ws_size,
                              hipStream_t stream) {
    const float* pred = (const float*)d_in[0];
    const float* tbox = (const float*)d_in[1];
    const float* tcls = (const float*)d_in[2];
    const int*   mask = (const int*)d_in[3];
    float* out = (float*)d_out;

    int cells = in_sizes[0] / 30;                 // N*S*S = 802816
    int n_img = cells / (SS * SS);                // N
    int nblocks = (cells + BLOCK - 1) / BLOCK;    // 3136

    float4* part = (float4*)d_ws;                 // nblocks * 16 bytes

    yolo_main<<<nblocks, BLOCK, 0, stream>>>(
        pred, (const float4*)tbox, (const float4*)tcls, mask, part, cells);
    yolo_final<<<1, BLOCK, 0, stream>>>(part, nblocks, out, 1.0f / (float)n_img);
}